// Round 4
// baseline (187.901 us; speedup 1.0000x reference)
//
#include <hip/hip_runtime.h>
#include <hip/hip_bf16.h>

// GATConv N=50000, C=64, H=12, E=400000 (+N self loops), x-space aggregation:
//   y[d] = concat_h[ (sum_e w_eh x[s_e]) / (den_h*H) ] @ Wstack,  h never built.
// R9 (176us): k_pre | k_main (adj build + ax-MFMA) | k_fused (4 waves x 4
//   nodes serial, readlane broadcast, 16x64x768 MFMA epilogue).
// R10 FAILED (201us), R11/R12 NEUTRAL: scratch / masking / uniformity
//   micro-theories all disproved. Surviving fact: ~5600 VALU instrs/wave vs
//   ~1600 in source; the per-(edge x head) readlane+FMA inner loop dominates.
// R13 (this round): DELETE the per-(edge,head) VALU work. Aggregation is
//   matmul-shaped: z[c][h] = sum_k x_{s_k}[c] * w_{k,h} = [64xK]@[Kx12],
//   K=deg<=32. Per node: stage gathered x rows TRANSPOSED into LDS
//   xsT[c][k] (lane=channel: 1 load + 1 ds_write_b16 per edge), weights
//   into wlds[h][k] (lane=edge as before), then 4 MFMAs (channel chunks)
//   + 1 MFMA with A=ones which yields den_h in every row (denominator
//   free -- no butterflies, no den-FMA). Dead k-slots killed by w=0;
//   one-time xsT zero-init guards stale-NaN (0*NaN). zt re-padded
//   (h-stride 72, row-stride 872) to keep all ds_read_b128 16B-aligned
//   and <=2-way banked; xsT k-offset XOR-swizzled vs (c>>2)&3 to break
//   the stride-40 8-way staging-write conflict. deg>32 (P~1e-9): second
//   K=32 pass accumulating into the same accs.
// No segment_max: exp(s)/sum exp(s) is exact here (logits O(few), fp32 exp).

typedef __bf16 bf16x8 __attribute__((ext_vector_type(8)));
typedef __bf16 bf16x2 __attribute__((ext_vector_type(2)));
typedef float  f32x4  __attribute__((ext_vector_type(4)));

#define HEADS 12
#define CH 64
#define HC 768
#define CAP 64
#define ACOLS 24      // a_all[n][0..11]=src logits, [12..23]=dst logits
#define ZST 872       // zt row stride (bf16): 12 h-blocks of 72 + pad; 436dw%32=20 -> 2-way
#define HST 72        // zt per-head stride (64 data + 8 pad, 16B-aligned blocks)
#define XST 40        // xsT row stride (32 slots + 8 pad)
#define WST 40        // wlds row stride
// xsT swizzle: XOR slot bits 3..4 with (channel>>2)&3 -> breaks stride-40
// 8-way bank conflict on staging writes; preserves 8-elem contiguity.
#define XSW(c, i) ((c) * XST + ((i) ^ ((((c) >> 2) & 3) << 3)))

__global__ __launch_bounds__(256) void k_pre(
    const float* __restrict__ W,
    const float* __restrict__ att_src, const float* __restrict__ att_dst,
    int* __restrict__ cnt, __bf16* __restrict__ Wt2, __bf16* __restrict__ Vt,
    int N) {
    const int nb_z = (N + 255) >> 8;
    const int nb_w = (CH * HC) >> 8;           // 192
    int b = blockIdx.x, tid = threadIdx.x;
    if (b < nb_z) {                            // ---- cnt = 0 ----
        int i = b * 256 + tid;
        if (i < N) cnt[i] = 0;
        return;
    }
    b -= nb_z;
    if (b < nb_w) {                            // ---- Wt2 transpose ----
        int t = b * 256 + tid;
        int c = t / HC, kk = t % HC;
        int k = kk & 63;
        Wt2[t] = (__bf16)W[(size_t)k * HC + (kk - k) + c];
        return;
    }
    b -= nb_w;                                 // ---- Vt col b (0..31) ----
    if (b >= 2 * HEADS) {
        if (tid < CH) Vt[b * CH + tid] = (__bf16)0.f;
        return;
    }
    const float* att = (b < HEADS) ? att_src + b * CH
                                   : att_dst + (b - HEADS) * CH;
    int k = tid >> 2, cq = tid & 3;            // 64 k-rows x 4 c-quarters
    const float* wr = W + (size_t)k * HC + (b % HEADS) * CH + cq * 16;
    float s = 0.f;
#pragma unroll
    for (int j = 0; j < 16; ++j) s += wr[j] * att[cq * 16 + j];
    s += __shfl_xor(s, 1, 64);
    s += __shfl_xor(s, 2, 64);
    if (cq == 0) Vt[b * CH + k] = (__bf16)s;
}

__global__ __launch_bounds__(256) void k_main(
    const float* __restrict__ x, const int* __restrict__ ei,
    const __bf16* __restrict__ Vt,
    int* __restrict__ cnt, int* __restrict__ adj,
    __bf16* __restrict__ xb, float* __restrict__ a_all, int N, int E) {
    const int EP = E + N;
    const int nb_build = (EP + 255) >> 8;
    int b = blockIdx.x, tid = threadIdx.x;

    if (b < nb_build) {                        // ---- adjacency: SOURCE ids ----
        int e = b * 256 + tid;
        if (e < EP) {
            int d, s;
            if (e < E) { d = ei[E + e]; s = ei[e]; }
            else       { d = e - E;     s = d; }
            int pos = atomicAdd(&cnt[d], 1);
            if (pos < CAP) adj[d * CAP + pos] = s;
        }
        return;
    }
    b -= nb_build;                             // ---- a_all = x@V + xb ----
    int wave = tid >> 6, lane = tid & 63;
    int m = lane & 15, quad = lane >> 4;
    int m0 = b * 64 + wave * 16;
    int row = m0 + m;
    int rc = row < N ? row : N - 1;
    const float* xa = x + (size_t)rc * CH + quad * 8;
    f32x4 v0 = *(const f32x4*)xa;
    f32x4 v1 = *(const f32x4*)(xa + 4);
    f32x4 v2 = *(const f32x4*)(xa + 32);
    f32x4 v3 = *(const f32x4*)(xa + 36);
    bf16x8 a0, a1;
#pragma unroll
    for (int j = 0; j < 4; ++j) {
        a0[j] = (__bf16)v0[j]; a0[4 + j] = (__bf16)v1[j];
        a1[j] = (__bf16)v2[j]; a1[4 + j] = (__bf16)v3[j];
    }
    if (row < N) {                             // fused xb = bf16(x)
        *(bf16x8*)(xb + (size_t)row * CH + quad * 8) = a0;
        *(bf16x8*)(xb + (size_t)row * CH + quad * 8 + 32) = a1;
    }
#pragma unroll
    for (int t = 0; t < 2; ++t) {              // two 16-col tiles -> 24 cols
        const __bf16* bp = Vt + (size_t)(t * 16 + m) * CH + quad * 8;
        bf16x8 b0 = *(const bf16x8*)bp;
        bf16x8 b1 = *(const bf16x8*)(bp + 32);
        f32x4 acc = {0.f, 0.f, 0.f, 0.f};
        acc = __builtin_amdgcn_mfma_f32_16x16x32_bf16(a0, b0, acc, 0, 0, 0);
        acc = __builtin_amdgcn_mfma_f32_16x16x32_bf16(a1, b1, acc, 0, 0, 0);
        int col = t * 16 + m;
        if (col < ACOLS) {
#pragma unroll
            for (int r = 0; r < 4; ++r) {
                int rr = m0 + quad * 4 + r;
                if (rr < N) a_all[(size_t)rr * ACOLS + col] = acc[r];
            }
        }
    }
}

__global__ __launch_bounds__(256) void k_fused(
    const int* __restrict__ cnt, const int* __restrict__ adj,
    const float* __restrict__ a_all,
    const __bf16* __restrict__ xb, const __bf16* __restrict__ Wt2,
    const float* __restrict__ x, const float* __restrict__ bias,
    float* __restrict__ out, int N) {
    __shared__ __bf16 zt[16 * ZST];            // 27904 B
    __shared__ __bf16 xs_all[4][CH * XST];     // 20480 B (per-wave X^T tiles)
    __shared__ __bf16 wl_all[4][16 * WST];     //  5120 B (per-wave weight tiles)
    int lane = threadIdx.x & 63;
    int wave = __builtin_amdgcn_readfirstlane(threadIdx.x >> 6);
    int base = blockIdx.x * 16;
    __bf16* xs = xs_all[wave];
    __bf16* wl = wl_all[wave];

    // one-time zero of xs slots (stale/uninit-NaN guard: w=0 * NaN = NaN)
    {
        unsigned* xz = (unsigned*)(xs + lane * XST);
#pragma unroll
        for (int t = 0; t < 16; ++t) xz[t] = 0u;
    }

    // A-frag of all-ones: den MFMA yields den_h replicated in every row
    bf16x8 ones;
#pragma unroll
    for (int jj = 0; jj < 8; ++jj) ones[jj] = (__bf16)1.0f;

    // ---- prologue: 4 nodes' cnt + adj[0..31] in parallel ----
    int degj[4], slj[4];
#pragma unroll
    for (int j = 0; j < 4; ++j) {
        int d = base + wave * 4 + j;
        int dg = __builtin_amdgcn_readfirstlane(cnt[d]);
        degj[j] = dg < CAP ? dg : CAP;
        int sraw = 0;
        if (lane < 32) sraw = adj[d * CAP + lane];   // slots 0..31
        slj[j] = sraw < 0 ? 0 : (sraw >= N ? N - 1 : sraw);
    }

    const unsigned short* xbu = (const unsigned short*)xb;

#pragma unroll
    for (int j = 0; j < 4; ++j) {
        int nodeRow = wave * 4 + j;
        int d = base + nodeRow;
        int deg = degj[j];

        // d-side logits (uniform-address broadcast load), hoisted over passes
        float adf[HEADS];
        {
            const f32x4* p = (const f32x4*)(a_all + (size_t)d * ACOLS + HEADS);
            f32x4 q0 = p[0], q1 = p[1], q2 = p[2];
#pragma unroll
            for (int u = 0; u < 4; ++u) { adf[u] = q0[u]; adf[4 + u] = q1[u]; adf[8 + u] = q2[u]; }
        }

        f32x4 acc0 = {0.f,0.f,0.f,0.f}, acc1 = {0.f,0.f,0.f,0.f};
        f32x4 acc2 = {0.f,0.f,0.f,0.f}, acc3 = {0.f,0.f,0.f,0.f};
        f32x4 accden = {0.f,0.f,0.f,0.f};

        // ---- one K=32 pass: weights->wlds, gather->xsT, 5 MFMAs ----
        auto do_pass = [&](int s_ll, int dc) {
            // weights: lane = slot
            f32x4 t0 = {0.f,0.f,0.f,0.f}, t1 = {0.f,0.f,0.f,0.f}, t2 = {0.f,0.f,0.f,0.f};
            if (lane < dc) {
                const f32x4* p = (const f32x4*)(a_all + (size_t)s_ll * ACOLS);
                t0 = p[0]; t1 = p[1]; t2 = p[2];
            }
            float wv[HEADS];
#pragma unroll
            for (int u = 0; u < 4; ++u) {
                wv[u]     = t0[u] + adf[u];
                wv[4 + u] = t1[u] + adf[4 + u];
                wv[8 + u] = t2[u] + adf[8 + u];
            }
#pragma unroll
            for (int hh = 0; hh < HEADS; ++hh) {
                float sc = wv[hh];
                sc = sc > 0.f ? sc : 0.2f * sc;
                wv[hh] = (lane < dc) ? __expf(sc) : 0.f;   // dead slots -> 0
            }
            if (lane < 32) {
#pragma unroll
                for (int hh = 0; hh < HEADS; ++hh)
                    wl[hh * WST + lane] = (__bf16)wv[hh];
            }
            // stage x rows transposed: lane = channel, slot i
            int i = 0;
            for (; i + 3 < dc; i += 4) {
                int s0 = __builtin_amdgcn_readlane(s_ll, i);
                int s1 = __builtin_amdgcn_readlane(s_ll, i + 1);
                int s2 = __builtin_amdgcn_readlane(s_ll, i + 2);
                int s3 = __builtin_amdgcn_readlane(s_ll, i + 3);
                unsigned u0 = xbu[(size_t)s0 * CH + lane];
                unsigned u1 = xbu[(size_t)s1 * CH + lane];
                unsigned u2 = xbu[(size_t)s2 * CH + lane];
                unsigned u3 = xbu[(size_t)s3 * CH + lane];
                unsigned* dst = (unsigned*)(xs + XSW(lane, i));
                dst[0] = u0 | (u1 << 16);
                dst[1] = u2 | (u3 << 16);
            }
            for (; i < dc; ++i) {
                int s = __builtin_amdgcn_readlane(s_ll, i);
                xs[XSW(lane, i)] = xb[(size_t)s * CH + lane];
            }
            // fragments + MFMA (wave-private LDS; compiler inserts lgkmcnt)
            int hq = lane & 15, q = lane >> 4;
            bf16x8 bfrag = *(const bf16x8*)(wl + hq * WST + q * 8);
            {
                int row = hq;
                bf16x8 a = *(const bf16x8*)(xs + row * XST + ((q * 8) ^ (((row >> 2) & 3) << 3)));
                acc0 = __builtin_amdgcn_mfma_f32_16x16x32_bf16(a, bfrag, acc0, 0, 0, 0);
            }
            {
                int row = 16 + hq;
                bf16x8 a = *(const bf16x8*)(xs + row * XST + ((q * 8) ^ (((row >> 2) & 3) << 3)));
                acc1 = __builtin_amdgcn_mfma_f32_16x16x32_bf16(a, bfrag, acc1, 0, 0, 0);
            }
            {
                int row = 32 + hq;
                bf16x8 a = *(const bf16x8*)(xs + row * XST + ((q * 8) ^ (((row >> 2) & 3) << 3)));
                acc2 = __builtin_amdgcn_mfma_f32_16x16x32_bf16(a, bfrag, acc2, 0, 0, 0);
            }
            {
                int row = 48 + hq;
                bf16x8 a = *(const bf16x8*)(xs + row * XST + ((q * 8) ^ (((row >> 2) & 3) << 3)));
                acc3 = __builtin_amdgcn_mfma_f32_16x16x32_bf16(a, bfrag, acc3, 0, 0, 0);
            }
            accden = __builtin_amdgcn_mfma_f32_16x16x32_bf16(ones, bfrag, accden, 0, 0, 0);
        };

        int dc0 = deg < 32 ? deg : 32;
        do_pass(slj[j], dc0);
        if (deg > 32) {                          // ~never (Poisson(9))
            int s2 = 0;
            if (lane < 32) {
                s2 = adj[d * CAP + 32 + lane];
                s2 = s2 < 0 ? 0 : (s2 >= N ? N - 1 : s2);
            }
            do_pass(s2, deg - 32);
        }

        // ---- epilogue: normalize + packed zt write ----
        // C layout: col = lane&15 = head, row = (lane>>4)*4+r = channel-in-chunk
        float den = accden[0];
        float rinv = 1.0f / ((den + 1e-16f) * (float)HEADS);
        int h = lane & 15, q = lane >> 4;
        if (h < HEADS) {
            __bf16* zr = zt + nodeRow * ZST + h * HST + q * 4;
            f32x4 av[4] = {acc0, acc1, acc2, acc3};
#pragma unroll
            for (int t = 0; t < 4; ++t) {
                bf16x2 p0, p1;
                p0[0] = (__bf16)(av[t][0] * rinv);
                p0[1] = (__bf16)(av[t][1] * rinv);
                p1[0] = (__bf16)(av[t][2] * rinv);
                p1[1] = (__bf16)(av[t][3] * rinv);
                *(bf16x2*)(zr + t * 16) = p0;
                *(bf16x2*)(zr + t * 16 + 2) = p1;
            }
        }
    }

    __syncthreads();

    // ---- phase 3: 16x64x768 GEMM; wave = one 16-col tile ----
    {
        int m = lane & 15, quad = lane >> 4;
        int n0 = wave * 16;
        const __bf16* za = zt + m * ZST + quad * 8;
        const __bf16* wb = Wt2 + (size_t)(n0 + m) * HC + quad * 8;
        f32x4 acc = {0.f, 0.f, 0.f, 0.f};
#pragma unroll
        for (int kc = 0; kc < HC; kc += 32) {
            int koff = ((kc >> 6) * HST) + (kc & 63);   // h-padded zt offset
            bf16x8 a  = *(const bf16x8*)(za + koff);
            bf16x8 bf = *(const bf16x8*)(wb + kc);
            acc = __builtin_amdgcn_mfma_f32_16x16x32_bf16(a, bf, acc, 0, 0, 0);
        }
        int col = n0 + m;
        float bv = bias[col];
#pragma unroll
        for (int r = 0; r < 4; ++r) {
            int dd = base + quad * 4 + r;
            if (dd < N) {
                float o = x[(size_t)dd * CH + col] + acc[r] + bv;
                out[(size_t)dd * CH + col] = fmaxf(o, 0.f);
            }
        }
    }
}

extern "C" void kernel_launch(void* const* d_in, const int* in_sizes, int n_in,
                              void* d_out, int out_size, void* d_ws, size_t ws_size,
                              hipStream_t stream) {
    const float* x       = (const float*)d_in[0];
    const int*   ei      = (const int*)d_in[1];
    const float* W       = (const float*)d_in[2];
    const float* att_src = (const float*)d_in[3];
    const float* att_dst = (const float*)d_in[4];
    const float* bias    = (const float*)d_in[5];
    float* out = (float*)d_out;

    int N = in_sizes[0] / CH;   // 50000
    int E = in_sizes[1] / 2;    // 400000
    int EP = E + N;

    char* ws = (char*)d_ws;
    size_t off = 0;
    auto take = [&](size_t bytes) -> void* {
        void* p = ws + off;
        off = (off + bytes + 255) & ~(size_t)255;
        return p;
    };
    __bf16* xb    = (__bf16*)take((size_t)N * CH * sizeof(__bf16));
    __bf16* Wt2   = (__bf16*)take((size_t)CH * HC * sizeof(__bf16));
    __bf16* Vt    = (__bf16*)take((size_t)32 * CH * sizeof(__bf16));
    float*  a_all = (float*)take((size_t)N * ACOLS * sizeof(float));
    int*    adj   = (int*)take((size_t)N * CAP * sizeof(int));
    int*    cnt   = (int*)take((size_t)N * sizeof(int));

    const int nb_z     = (N + 255) / 256;
    const int nb_w     = (CH * HC) / 256;
    const int nb_build = (EP + 255) / 256;
    const int nb_ax    = (N + 63) / 64;

    k_pre<<<nb_z + nb_w + 32, 256, 0, stream>>>(W, att_src, att_dst, cnt, Wt2, Vt, N);
    k_main<<<nb_build + nb_ax, 256, 0, stream>>>(x, ei, Vt, cnt, adj, xb, a_all, N, E);
    k_fused<<<(N + 15) / 16, 256, 0, stream>>>(cnt, adj, a_all, xb, Wt2, x, bias, out, N);
}